// Round 11
// baseline (384.025 us; speedup 1.0000x reference)
//
#include <hip/hip_runtime.h>
#include <hip/hip_fp16.h>

// Problem constants
#define NV    884736     // 96^3 voxels
#define NB    3456       // NV / 256
#define DIM   96
#define DIM2  9216       // 96*96
#define NF    6          // fields actually needed: pos1,pos2,pos3,neg0,neg1,neg2
#define SLACK 32         // uint2 pad entries after each buffer (zeroed in init)

// Intermediate fields stored as half4 (x,y,z,pad) = 8 B/voxel.
// A z-adjacent voxel PAIR is 16 contiguous bytes -> one dwordx4 gather
// covers both z-corners of a trilinear cell. 4 gathers/sample, not 8.
//
// Empirical laws from rounds 0-10 (MI355X):
// - XCD-chunked contiguous work order per XCD L2: ~1.7x on steps. Keep.
// - Monolithic loss thread (6 pairs) beats pair-split 2.4x; half-splitting
//   the loss costs +7.6us. Keep single NB-block launch.
// - VPT=1 == VPT=2; nt-stores +17% worse; persistent loops 4x worse;
//   LDS-staging R neutral; loss SW-pipelining neutral. Don't.
// - Round-10 crash lesson: LDS uint4 stores MUST be 16B-aligned; a row
//   stride of 776 (8 mod 16) hard-faults. ROWB must be a multiple of 16.
// - THIS ROUND (fixed): tile steps 0-5 in LDS (3 planes x 6 rows staged
//   coalesced; DS-pipe reads replace divergent TA gathers; bit-exact
//   per-thread global fallback for |v|>=1). Plain kernel for step 6.

union H4 { uint2 u; __half2 h2[2]; };   // one voxel (8 B)
union H8 { uint4 u; __half2 h2[4]; };   // two z-adjacent voxels (16 B)

struct F3 { float x, y, z; };

__device__ __forceinline__ F3 lerp3(F3 a, F3 b, float t, float omt) {
    F3 r;
    r.x = a.x * omt + b.x * t;
    r.y = a.y * omt + b.y * t;
    r.z = a.z * omt + b.z * t;
    return r;
}

__device__ __forceinline__ uint2 pack_h4(float x, float y, float z) {
    H4 v;
    v.h2[0] = __floats2half2_rn(x, y);
    v.h2[1] = __floats2half2_rn(z, 0.0f);
    return v.u;
}

__device__ __forceinline__ F3 unpack_h4(uint2 raw) {
    H4 v; v.u = raw;
    float2 xy = __half22float2(v.h2[0]);
    float2 zp = __half22float2(v.h2[1]);
    F3 r; r.x = xy.x; r.y = xy.y; r.z = zp.x;
    return r;
}

// Border semantics EXACTLY as the reference:
//   x0 = clamp((int)floor(x),0,95); x1 = min(x0+1,95); fx = x - floor(x)
// z edge: when z0==95 force fz=0 so the second voxel of the 16B pair
// (next row / zeroed pad) is multiplied by 0.
struct TriIdx { int idx[4]; float fx, fy, fz; };

__device__ __forceinline__ TriIdx tri_prep(float x, float y, float z) {
    TriIdx t;
    float xf = floorf(x), yf = floorf(y), zf = floorf(z);
    t.fx = x - xf; t.fy = y - yf;
    float fz = z - zf;
    int x0 = (int)xf; x0 = x0 < 0 ? 0 : (x0 > DIM - 1 ? DIM - 1 : x0);
    int y0 = (int)yf; y0 = y0 < 0 ? 0 : (y0 > DIM - 1 ? DIM - 1 : y0);
    int z0 = (int)zf; z0 = z0 < 0 ? 0 : (z0 > DIM - 1 ? DIM - 1 : z0);
    int x1 = x0 + 1; if (x1 > DIM - 1) x1 = DIM - 1;
    int y1 = y0 + 1; if (y1 > DIM - 1) y1 = DIM - 1;
    t.fz = (z0 < DIM - 1) ? fz : 0.0f;
    int X0 = x0 * DIM2, X1 = x1 * DIM2;
    int Y0 = y0 * DIM,  Y1 = y1 * DIM;
    t.idx[0] = X0 + Y0 + z0;   // c00* pair
    t.idx[1] = X0 + Y1 + z0;   // c01* pair
    t.idx[2] = X1 + Y0 + z0;   // c10* pair
    t.idx[3] = X1 + Y1 + z0;   // c11* pair
    return t;
}

__device__ __forceinline__ void tri_gather(const uint2* __restrict__ f,
                                           const TriIdx& t, H8 c[4]) {
    #pragma unroll
    for (int q = 0; q < 4; q++)
        c[q].u = *(const uint4*)(f + t.idx[q]);   // 16B: voxels z0, z0+1
}

__device__ __forceinline__ F3 tri_combine(const TriIdx& t, const H8 c[4]) {
    float gz = 1.0f - t.fz, gy = 1.0f - t.fy, gx = 1.0f - t.fx;
    F3 pz[4];
    #pragma unroll
    for (int q = 0; q < 4; q++) {
        float2 xy0 = __half22float2(c[q].h2[0]);
        float2 z0p = __half22float2(c[q].h2[1]);
        float2 xy1 = __half22float2(c[q].h2[2]);
        float2 z1p = __half22float2(c[q].h2[3]);
        F3 lo; lo.x = xy0.x; lo.y = xy0.y; lo.z = z0p.x;
        F3 hi; hi.x = xy1.x; hi.y = xy1.y; hi.z = z1p.x;
        pz[q] = lerp3(lo, hi, t.fz, gz);
    }
    F3 c0 = lerp3(pz[0], pz[1], t.fy, gy);
    F3 c1 = lerp3(pz[2], pz[3], t.fy, gy);
    return lerp3(c0, c1, t.fx, gx);
}

// Init: v0 = +T/128 for transforms 1..3 -> fields 0..2,
//       v0 = -T/128 for transforms 0..2 -> fields 3..5.
__global__ __launch_bounds__(256) void init_kernel(const float* __restrict__ T,
                                                   uint2* __restrict__ bufA,
                                                   uint2* __restrict__ bufB,
                                                   float* __restrict__ out) {
    int t = blockIdx.y;                       // transform 0..3
    int l = blockIdx.x * 256 + threadIdx.x;   // voxel linear index
    if (t == 0 && l == 0) out[0] = 0.0f;
    if (t == 0 && l < SLACK) {
        bufA[(size_t)NF * NV + l] = make_uint2(0u, 0u);
        bufB[(size_t)NF * NV + l] = make_uint2(0u, 0u);
    }
    const float inv = 1.0f / 128.0f;
    float vx = T[(size_t)(t * 3 + 0) * NV + l] * inv;
    float vy = T[(size_t)(t * 3 + 1) * NV + l] * inv;
    float vz = T[(size_t)(t * 3 + 2) * NV + l] * inv;
    if (t >= 1) bufA[(size_t)(t - 1) * NV + l] = pack_h4( vx,  vy,  vz);
    if (t <= 2) bufA[(size_t)(t + 3) * NV + l] = pack_h4(-vx, -vy, -vz);
}

#define STEP_VB   NB                      // 3456 voxel-blocks per field
#define STEP_W    (STEP_VB * NF)          // 20736 work units
#define STEP_CHK  (STEP_W / 8)            // 2592 per XCD

// Plain step (round-3 proven form) -- used for step 6 (large displacements).
__global__ __launch_bounds__(256) void step_kernel(const uint2* __restrict__ src,
                                                   uint2* __restrict__ dst) {
    int b   = blockIdx.x;
    int w   = (b & 7) * STEP_CHK + (b >> 3);
    int f   = w / STEP_VB;
    int vb  = w - f * STEP_VB;
    const uint2* __restrict__ s = src + (size_t)f * NV;
    uint2*       __restrict__ d = dst + (size_t)f * NV;

    int l   = vb * 256 + threadIdx.x;
    int i   = l / DIM2;
    int rem = l - i * DIM2;
    int j   = rem / DIM;
    int k   = rem - j * DIM;

    F3 v = unpack_h4(s[l]);
    TriIdx t = tri_prep((float)i + v.x, (float)j + v.y, (float)k + v.z);
    H8 c[4];
    tri_gather(s, t, c);
    F3 smp = tri_combine(t, c);
    d[l] = pack_h4(v.x + smp.x, v.y + smp.y, v.z + smp.z);
}

// Tiled step: stage 3 planes x 6 rows x (96 voxels + 16B zero pad) in LDS;
// gathers become DS reads when the cell is in-tile (|v|<1 componentwise),
// bit-exact per-thread global fallback otherwise.
//   tile row index = (x0-(i-1))*6 + (y0-(jb-1)); row stride 784 B (16-mult!).
//   Clamped-source staging duplicates edge planes/rows -> x1=min(x0+1,95)
//   and y1=min(y0+1,95) are simply +1 plane/row reads. Row pad (bytes
//   768..783, zeroed) makes the z0==95 pair-read match the global fz=0 trick.
#define TROWS     18                      // 3 planes * 6 rows
#define ROWB      784                     // 96*8 + 16 pad  (multiple of 16!)
#define TILE_B    (TROWS * ROWB)          // 14112 B
#define TCHUNKS   (TROWS * 48)            // 864 16B chunks (96 voxels/row)
__global__ __launch_bounds__(256) void step_tiled_kernel(const uint2* __restrict__ src,
                                                         uint2* __restrict__ dst) {
    __shared__ __align__(16) unsigned char tile[TILE_B];
    int tid = threadIdx.x;
    int b   = blockIdx.x;
    int w   = (b & 7) * STEP_CHK + (b >> 3);
    int f   = w / STEP_VB;
    int vb  = w - f * STEP_VB;
    const uint2* __restrict__ s = src + (size_t)f * NV;
    uint2*       __restrict__ d = dst + (size_t)f * NV;

    int l0   = vb * 256;
    int i    = l0 / DIM2;            // DIM2 = 36*256 -> block never straddles planes
    int rem0 = l0 - i * DIM2;
    int jb   = rem0 / DIM;           // first row touched by this block

    // ---- stage neighborhood: planes i-1..i+1 (clamped), rows jb-1..jb+4 (clamped)
    #pragma unroll
    for (int rnd = 0; rnd < 4; rnd++) {
        int c = rnd * 256 + tid;
        if (c < TCHUNKS) {
            int r   = c / 48;
            int col = c - r * 48;
            int p   = r / 6;
            int rr  = r - p * 6;
            int ic  = i - 1 + p;  ic = ic < 0 ? 0 : (ic > DIM - 1 ? DIM - 1 : ic);
            int jc  = jb - 1 + rr; jc = jc < 0 ? 0 : (jc > DIM - 1 ? DIM - 1 : jc);
            uint4 val = *(const uint4*)(s + ic * DIM2 + jc * DIM + col * 2);
            *(uint4*)(tile + r * ROWB + col * 16) = val;   // 16B-aligned (ROWB%16==0)
        }
    }
    if (tid < TROWS)
        *(uint4*)(tile + tid * ROWB + 768) = make_uint4(0u, 0u, 0u, 0u);
    __syncthreads();

    int remt = rem0 + tid;
    int j = remt / DIM;
    int k = remt - j * DIM;

    // own voxel from the tile: plane 1, row j-(jb-1), entry k
    F3 v = unpack_h4(*(const uint2*)(tile + (6 + (j - jb + 1)) * ROWB + k * 8));

    float x = (float)i + v.x, y = (float)j + v.y, z = (float)k + v.z;
    float xf = floorf(x), yf = floorf(y), zf = floorf(z);
    TriIdx t;
    t.fx = x - xf; t.fy = y - yf;
    float fzr = z - zf;
    int x0 = (int)xf; x0 = x0 < 0 ? 0 : (x0 > DIM - 1 ? DIM - 1 : x0);
    int y0 = (int)yf; y0 = y0 < 0 ? 0 : (y0 > DIM - 1 ? DIM - 1 : y0);
    int z0 = (int)zf; z0 = z0 < 0 ? 0 : (z0 > DIM - 1 ? DIM - 1 : z0);
    t.fz = (z0 < DIM - 1) ? fzr : 0.0f;

    // in-tile test (clamped coords land in-tile with reference-identical values)
    unsigned ux = (unsigned)(x0 - (i - 1));
    unsigned uy = (unsigned)(y0 - (j - 1));
    unsigned uz = (unsigned)(z0 - (k - 1));
    bool in_tile = (ux <= 1u) & (uy <= 1u) & (uz <= 1u);

    H8 c[4];
    if (in_tile) {
        int b00 = ((x0 - (i - 1)) * 6 + (y0 - (jb - 1))) * ROWB + z0 * 8;
        c[0].h2[0] = ((const __half2*)(tile + b00))[0];
        c[0].h2[1] = ((const __half2*)(tile + b00))[1];
        c[0].h2[2] = ((const __half2*)(tile + b00 + 8))[0];
        c[0].h2[3] = ((const __half2*)(tile + b00 + 8))[1];
        int b01 = b00 + ROWB;          // y1 = y0+1 (duplicated row at edge)
        c[1].h2[0] = ((const __half2*)(tile + b01))[0];
        c[1].h2[1] = ((const __half2*)(tile + b01))[1];
        c[1].h2[2] = ((const __half2*)(tile + b01 + 8))[0];
        c[1].h2[3] = ((const __half2*)(tile + b01 + 8))[1];
        int b10 = b00 + 6 * ROWB;      // x1 = x0+1 (duplicated plane at edge)
        c[2].h2[0] = ((const __half2*)(tile + b10))[0];
        c[2].h2[1] = ((const __half2*)(tile + b10))[1];
        c[2].h2[2] = ((const __half2*)(tile + b10 + 8))[0];
        c[2].h2[3] = ((const __half2*)(tile + b10 + 8))[1];
        int b11 = b10 + ROWB;
        c[3].h2[0] = ((const __half2*)(tile + b11))[0];
        c[3].h2[1] = ((const __half2*)(tile + b11))[1];
        c[3].h2[2] = ((const __half2*)(tile + b11 + 8))[0];
        c[3].h2[3] = ((const __half2*)(tile + b11 + 8))[1];
    } else {
        int x1 = x0 + 1; if (x1 > DIM - 1) x1 = DIM - 1;
        int y1 = y0 + 1; if (y1 > DIM - 1) y1 = DIM - 1;
        t.idx[0] = x0 * DIM2 + y0 * DIM + z0;
        t.idx[1] = x0 * DIM2 + y1 * DIM + z0;
        t.idx[2] = x1 * DIM2 + y0 * DIM + z0;
        t.idx[3] = x1 * DIM2 + y1 * DIM + z0;
        tri_gather(s, t, c);
    }
    F3 smp = tri_combine(t, c);
    d[l0 + tid] = pack_h4(v.x + smp.x, v.y + smp.y, v.z + smp.z);
}

// Compose + residual + loss for all 6 pairs, one thread per voxel
// (round-3/8 proven monolithic body, 56us), XCD-chunked swizzle.
__global__ __launch_bounds__(256) void loss_kernel(const uint2* __restrict__ fields,
                                                   const float* __restrict__ R,
                                                   float* __restrict__ out) {
    int b = blockIdx.x;
    int vb = (b & 7) * (NB / 8) + (b >> 3);   // bijective XCD-chunked swizzle
    int l = vb * 256 + threadIdx.x;
    int k = l % DIM;
    int j = (l / DIM) % DIM;
    int i = l / DIM2;
    float fi = (float)i, fj = (float)j, fk = (float)k;

    F3 f1c[3];
    #pragma unroll
    for (int r = 0; r < 3; r++)
        f1c[r] = unpack_h4(fields[(size_t)(3 + r) * NV + l]);

    float rbuf[18];
    const float* Rl = R + (size_t)l * 18;
    #pragma unroll
    for (int q = 0; q < 18; q++) rbuf[q] = Rl[q];

    const int REFI[6] = {0, 0, 0, 1, 1, 2};
    const int FLOF[6] = {0, 1, 2, 1, 2, 2};

    float acc = 0.0f;
    #pragma unroll
    for (int p = 0; p < 6; p += 2) {
        F3 f1a = f1c[REFI[p]];
        F3 f1b = f1c[REFI[p + 1]];
        const uint2* __restrict__ f2a = fields + (size_t)FLOF[p]     * NV;
        const uint2* __restrict__ f2b = fields + (size_t)FLOF[p + 1] * NV;
        TriIdx ta = tri_prep(fi + f1a.x, fj + f1a.y, fk + f1a.z);
        TriIdx tb = tri_prep(fi + f1b.x, fj + f1b.y, fk + f1b.z);
        H8 ca[4], cb[4];
        tri_gather(f2a, ta, ca);
        tri_gather(f2b, tb, cb);
        F3 sa = tri_combine(ta, ca);
        F3 sb = tri_combine(tb, cb);
        float rx = f1a.x + sa.x - rbuf[0 * 6 + p];
        float ry = f1a.y + sa.y - rbuf[1 * 6 + p];
        float rz = f1a.z + sa.z - rbuf[2 * 6 + p];
        acc += sqrtf(rx * rx + ry * ry + rz * rz);
        rx = f1b.x + sb.x - rbuf[0 * 6 + p + 1];
        ry = f1b.y + sb.y - rbuf[1 * 6 + p + 1];
        rz = f1b.z + sb.z - rbuf[2 * 6 + p + 1];
        acc += sqrtf(rx * rx + ry * ry + rz * rz);
    }

    __shared__ float wsum[4];
    int lane = threadIdx.x & 63;
    int wid  = threadIdx.x >> 6;
    #pragma unroll
    for (int off = 32; off > 0; off >>= 1)
        acc += __shfl_down(acc, off, 64);
    if (lane == 0) wsum[wid] = acc;
    __syncthreads();
    if (threadIdx.x == 0) {
        float s = wsum[0] + wsum[1] + wsum[2] + wsum[3];
        atomicAdd(out, s);
    }
}

extern "C" void kernel_launch(void* const* d_in, const int* in_sizes, int n_in,
                              void* d_out, int out_size, void* d_ws, size_t ws_size,
                              hipStream_t stream) {
    const float* T = (const float*)d_in[0];   // (4,3,96,96,96) fp32
    const float* R = (const float*)d_in[1];   // (96,96,96,3,6) fp32
    float* out = (float*)d_out;               // scalar loss

    uint2* bufA = (uint2*)d_ws;
    uint2* bufB = bufA + (size_t)NF * NV + SLACK;

    dim3 blk(256);
    init_kernel<<<dim3(NB, 4), blk, 0, stream>>>(T, bufA, bufB, out);

    uint2* src = bufA;
    uint2* dst = bufB;
    for (int s = 0; s < 7; s++) {
        if (s < 6)
            step_tiled_kernel<<<STEP_W, blk, 0, stream>>>(src, dst);
        else
            step_kernel<<<STEP_W, blk, 0, stream>>>(src, dst);
        uint2* tmp = src; src = dst; dst = tmp;
    }
    // After 7 steps (odd), final fields are in bufB == src.
    loss_kernel<<<NB, blk, 0, stream>>>(src, R, out);
}

// Round 12
// 346.734 us; speedup vs baseline: 1.1075x; 1.1075x over previous
//
#include <hip/hip_runtime.h>
#include <hip/hip_fp16.h>

// Problem constants
#define NV    884736     // 96^3 voxels
#define NB    3456       // NV / 256
#define DIM   96
#define DIM2  9216       // 96*96
#define NF    6          // fields actually needed: pos1,pos2,pos3,neg0,neg1,neg2
#define SLACK 32         // uint2 pad entries after each buffer (zeroed in init)

// Intermediate fields stored as half4 (x,y,z,pad) = 8 B/voxel.
// A z-adjacent voxel PAIR is 16 contiguous bytes -> one dwordx4 gather
// covers both z-corners of a trilinear cell. 4 gathers/sample, not 8.
//
// ONLY 6 of the 8 integrated fields are consumed by the loss:
//   F_pos[flo], flo in {1,2,3}  -> fields 0,1,2
//   F_neg[ref], ref in {0,1,2}  -> fields 3,4,5
//
// FINAL CONFIGURATION (proven best, 347 us). Empirical laws, rounds 0-11:
// - XCD-chunked contiguous work order per XCD L2: ~1.7x on steps, -38%
//   FETCH on loss. Kept everywhere.
// - Dead-field elimination (8->6 fields): -15%. Kept.
// - Refuted levers (each measured worse or neutral): VPT>1, loss
//   pair-splitting (2.4x worse), persistent work loops (4x worse,
//   compiler serializes gathers at VGPR=32), LDS-staging R (neutral),
//   loss SW-pipelining (neutral, compiler reuses payload regs),
//   nontemporal stores (+17%), LDS neighborhood tiling of steps (+12%;
//   DS-pipe cost + staging exceeds the divergent TA gather it replaces).
// - Steps (~40us each) sit ~15% above the most optimistic divergent-gather
//   floor (~35us); loss (56us) resisted 4 independent attacks. This
//   decomposition is at its structural limit on MI355X.

union H4 { uint2 u; __half2 h2[2]; };   // one voxel (8 B)
union H8 { uint4 u; __half2 h2[4]; };   // two z-adjacent voxels (16 B)

struct F3 { float x, y, z; };

__device__ __forceinline__ F3 lerp3(F3 a, F3 b, float t, float omt) {
    F3 r;
    r.x = a.x * omt + b.x * t;
    r.y = a.y * omt + b.y * t;
    r.z = a.z * omt + b.z * t;
    return r;
}

__device__ __forceinline__ uint2 pack_h4(float x, float y, float z) {
    H4 v;
    v.h2[0] = __floats2half2_rn(x, y);
    v.h2[1] = __floats2half2_rn(z, 0.0f);
    return v.u;
}

__device__ __forceinline__ F3 unpack_h4(uint2 raw) {
    H4 v; v.u = raw;
    float2 xy = __half22float2(v.h2[0]);
    float2 zp = __half22float2(v.h2[1]);
    F3 r; r.x = xy.x; r.y = xy.y; r.z = zp.x;
    return r;
}

// Phase-split trilinear sampling on half4 fields.
// Border semantics EXACTLY as the reference:
//   x0 = clamp((int)floor(x),0,95); x1 = min(x0+1,95); fx = x - floor(x)
// z edge: when z0==95 force fz=0 so the second voxel of the 16B pair
// (next row / zeroed pad) is multiplied by 0.
struct TriIdx { int idx[4]; float fx, fy, fz; };

__device__ __forceinline__ TriIdx tri_prep(float x, float y, float z) {
    TriIdx t;
    float xf = floorf(x), yf = floorf(y), zf = floorf(z);
    t.fx = x - xf; t.fy = y - yf;
    float fz = z - zf;
    int x0 = (int)xf; x0 = x0 < 0 ? 0 : (x0 > DIM - 1 ? DIM - 1 : x0);
    int y0 = (int)yf; y0 = y0 < 0 ? 0 : (y0 > DIM - 1 ? DIM - 1 : y0);
    int z0 = (int)zf; z0 = z0 < 0 ? 0 : (z0 > DIM - 1 ? DIM - 1 : z0);
    int x1 = x0 + 1; if (x1 > DIM - 1) x1 = DIM - 1;
    int y1 = y0 + 1; if (y1 > DIM - 1) y1 = DIM - 1;
    t.fz = (z0 < DIM - 1) ? fz : 0.0f;
    int X0 = x0 * DIM2, X1 = x1 * DIM2;
    int Y0 = y0 * DIM,  Y1 = y1 * DIM;
    t.idx[0] = X0 + Y0 + z0;   // c00* pair
    t.idx[1] = X0 + Y1 + z0;   // c01* pair
    t.idx[2] = X1 + Y0 + z0;   // c10* pair
    t.idx[3] = X1 + Y1 + z0;   // c11* pair
    return t;
}

__device__ __forceinline__ void tri_gather(const uint2* __restrict__ f,
                                           const TriIdx& t, H8 c[4]) {
    #pragma unroll
    for (int q = 0; q < 4; q++)
        c[q].u = *(const uint4*)(f + t.idx[q]);   // 16B: voxels z0, z0+1
}

__device__ __forceinline__ F3 tri_combine(const TriIdx& t, const H8 c[4]) {
    float gz = 1.0f - t.fz, gy = 1.0f - t.fy, gx = 1.0f - t.fx;
    F3 pz[4];
    #pragma unroll
    for (int q = 0; q < 4; q++) {
        float2 xy0 = __half22float2(c[q].h2[0]);
        float2 z0p = __half22float2(c[q].h2[1]);
        float2 xy1 = __half22float2(c[q].h2[2]);
        float2 z1p = __half22float2(c[q].h2[3]);
        F3 lo; lo.x = xy0.x; lo.y = xy0.y; lo.z = z0p.x;
        F3 hi; hi.x = xy1.x; hi.y = xy1.y; hi.z = z1p.x;
        pz[q] = lerp3(lo, hi, t.fz, gz);
    }
    F3 c0 = lerp3(pz[0], pz[1], t.fy, gy);
    F3 c1 = lerp3(pz[2], pz[3], t.fy, gy);
    return lerp3(c0, c1, t.fx, gx);
}

__device__ __forceinline__ float resid(F3 f1, F3 s, const float* rb, int p) {
    float rx = f1.x + s.x - rb[0 * 6 + p];
    float ry = f1.y + s.y - rb[1 * 6 + p];
    float rz = f1.z + s.z - rb[2 * 6 + p];
    return sqrtf(rx * rx + ry * ry + rz * rz);
}

// Init: v0 = +T/128 for transforms 1..3 -> fields 0..2,
//       v0 = -T/128 for transforms 0..2 -> fields 3..5.
// Also zeroes the loss accumulator and the 16B-overread pad of both buffers.
__global__ __launch_bounds__(256) void init_kernel(const float* __restrict__ T,
                                                   uint2* __restrict__ bufA,
                                                   uint2* __restrict__ bufB,
                                                   float* __restrict__ out) {
    int t = blockIdx.y;                       // transform 0..3
    int l = blockIdx.x * 256 + threadIdx.x;   // voxel linear index
    if (t == 0 && l == 0) out[0] = 0.0f;
    if (t == 0 && l < SLACK) {
        bufA[(size_t)NF * NV + l] = make_uint2(0u, 0u);
        bufB[(size_t)NF * NV + l] = make_uint2(0u, 0u);
    }
    const float inv = 1.0f / 128.0f;
    float vx = T[(size_t)(t * 3 + 0) * NV + l] * inv;
    float vy = T[(size_t)(t * 3 + 1) * NV + l] * inv;
    float vz = T[(size_t)(t * 3 + 2) * NV + l] * inv;
    if (t >= 1) bufA[(size_t)(t - 1) * NV + l] = pack_h4( vx,  vy,  vz);
    if (t <= 2) bufA[(size_t)(t + 3) * NV + l] = pack_h4(-vx, -vy, -vz);
}

// One scaling-and-squaring step for the 6 live fields (VPT=1, one unit per
// thread, XCD-chunked bijective swizzle, plain stores).
#define STEP_VB   NB                      // 3456 voxel-blocks per field
#define STEP_W    (STEP_VB * NF)          // 20736 work units
#define STEP_CHK  (STEP_W / 8)            // 2592 per XCD
__global__ __launch_bounds__(256) void step_kernel(const uint2* __restrict__ src,
                                                   uint2* __restrict__ dst) {
    int b   = blockIdx.x;
    int w   = (b & 7) * STEP_CHK + (b >> 3);
    int f   = w / STEP_VB;
    int vb  = w - f * STEP_VB;
    const uint2* __restrict__ s = src + (size_t)f * NV;
    uint2*       __restrict__ d = dst + (size_t)f * NV;

    int l   = vb * 256 + threadIdx.x;
    int i   = l / DIM2;
    int rem = l - i * DIM2;
    int j   = rem / DIM;
    int k   = rem - j * DIM;

    F3 v = unpack_h4(s[l]);
    TriIdx t = tri_prep((float)i + v.x, (float)j + v.y, (float)k + v.z);
    H8 c[4];
    tri_gather(s, t, c);
    F3 smp = tri_combine(t, c);
    d[l] = pack_h4(v.x + smp.x, v.y + smp.y, v.z + smp.z);
}

// Compose + residual + loss for all 6 pairs, one thread per voxel (monolithic
// -- the measured 2.4x winner over pair-splitting), XCD-chunked swizzle.
// Phases in SSA form; compiler schedules ~2 pairs of gathers in flight.
__global__ __launch_bounds__(256) void loss_kernel(const uint2* __restrict__ fields,
                                                   const float* __restrict__ R,
                                                   float* __restrict__ out) {
    int b = blockIdx.x;
    int vb = (b & 7) * (NB / 8) + (b >> 3);   // bijective XCD-chunked swizzle
    int l = vb * 256 + threadIdx.x;
    int k = l % DIM;
    int j = (l / DIM) % DIM;
    int i = l / DIM2;
    float fi = (float)i, fj = (float)j, fk = (float)k;

    // F_neg for ref indices 0,1,2 -> fields 3,4,5 (coalesced 8B loads)
    F3 f1c[3];
    #pragma unroll
    for (int r = 0; r < 3; r++)
        f1c[r] = unpack_h4(fields[(size_t)(3 + r) * NV + l]);

    // R is (96,96,96,3,6): 18 contiguous floats/voxel (compiler vectorizes).
    float rbuf[18];
    const float* Rl = R + (size_t)l * 18;
    #pragma unroll
    for (int q = 0; q < 18; q++) rbuf[q] = Rl[q];

    // The 3 warp positions.
    TriIdx t0 = tri_prep(fi + f1c[0].x, fj + f1c[0].y, fk + f1c[0].z);
    TriIdx t1 = tri_prep(fi + f1c[1].x, fj + f1c[1].y, fk + f1c[1].z);
    TriIdx t2 = tri_prep(fi + f1c[2].x, fj + f1c[2].y, fk + f1c[2].z);

    const uint2* __restrict__ F0 = fields + (size_t)0 * NV;
    const uint2* __restrict__ F1 = fields + (size_t)1 * NV;
    const uint2* __restrict__ F2 = fields + (size_t)2 * NV;

    // Issue phases 0 and 1 (pairs 0..3).
    H8 cA0[4], cB0[4], cA1[4], cB1[4];
    tri_gather(F0, t0, cA0);   // pair 0: (ref0, flo field 0)
    tri_gather(F1, t0, cB0);   // pair 1: (ref0, flo field 1)
    tri_gather(F2, t0, cA1);   // pair 2: (ref0, flo field 2)
    tri_gather(F1, t1, cB1);   // pair 3: (ref1, flo field 1)

    // Combine phase 0; issue phase 2 (pairs 4,5).
    F3 s0 = tri_combine(t0, cA0);
    F3 s1 = tri_combine(t0, cB0);
    H8 cA2[4], cB2[4];
    tri_gather(F2, t1, cA2);   // pair 4: (ref1, flo field 2)
    tri_gather(F2, t2, cB2);   // pair 5: (ref2, flo field 2)

    float acc = resid(f1c[0], s0, rbuf, 0) + resid(f1c[0], s1, rbuf, 1);

    F3 s2 = tri_combine(t0, cA1);
    F3 s3 = tri_combine(t1, cB1);
    acc += resid(f1c[0], s2, rbuf, 2) + resid(f1c[1], s3, rbuf, 3);

    F3 s4 = tri_combine(t1, cA2);
    F3 s5 = tri_combine(t2, cB2);
    acc += resid(f1c[1], s4, rbuf, 4) + resid(f1c[2], s5, rbuf, 5);

    // Block reduction: wave64 shuffle, then LDS across 4 waves, one atomic per block.
    __shared__ float wsum[4];
    int lane = threadIdx.x & 63;
    int wid  = threadIdx.x >> 6;
    #pragma unroll
    for (int off = 32; off > 0; off >>= 1)
        acc += __shfl_down(acc, off, 64);
    if (lane == 0) wsum[wid] = acc;
    __syncthreads();
    if (threadIdx.x == 0) {
        float s = wsum[0] + wsum[1] + wsum[2] + wsum[3];
        atomicAdd(out, s);
    }
}

extern "C" void kernel_launch(void* const* d_in, const int* in_sizes, int n_in,
                              void* d_out, int out_size, void* d_ws, size_t ws_size,
                              hipStream_t stream) {
    const float* T = (const float*)d_in[0];   // (4,3,96,96,96) fp32
    const float* R = (const float*)d_in[1];   // (96,96,96,3,6) fp32
    float* out = (float*)d_out;               // scalar loss

    // Workspace: two ping-pong buffers of 6 half4 fields.
    // Each buffer: 6 * 884736 * 8 B = 42.5 MB; +SLACK uint2 pad (zeroed) for
    // the 16B pair-gather that can read 8B past the last voxel.
    uint2* bufA = (uint2*)d_ws;
    uint2* bufB = bufA + (size_t)NF * NV + SLACK;

    dim3 blk(256);
    init_kernel<<<dim3(NB, 4), blk, 0, stream>>>(T, bufA, bufB, out);

    uint2* src = bufA;
    uint2* dst = bufB;
    for (int s = 0; s < 7; s++) {
        step_kernel<<<STEP_W, blk, 0, stream>>>(src, dst);
        uint2* tmp = src; src = dst; dst = tmp;
    }
    // After 7 steps (odd), final fields are in bufB == src.
    loss_kernel<<<NB, blk, 0, stream>>>(src, R, out);
}